// Round 17
// baseline (3244.931 us; speedup 1.0000x reference)
//
#include <hip/hip_runtime.h>
#include <hip/hip_fp16.h>

#define BATCH 1024
#define SEQ 512
#define NFEAT 24
#define NCELL 512
#define ZC 2048      // 4*NCELL
#define KP 544       // reordered K: [h(512) | x(24) | pad(8)]
#define NCH 17       // K chunks of 32
#define KL 576       // LDS k-stride in u16 (XOR-swizzled in 16B units)
#define DENSE_N 2048
#define PRED_N 576
#define NWG 256
#define NGRP 16      // row groups (64 rows each)
#define GWG 16       // WGs per group (128 z-cols each)
#define PFD 6        // A-prefetch depth in chunks
#define NBUF 7       // PFD + 1
#define RCH 8        // B chunks resident in VGPRs (256 regs; free at 1 wave/SIMD)

typedef unsigned short u16;
typedef unsigned int u32;
typedef unsigned long long u64;
typedef unsigned short u16x8 __attribute__((ext_vector_type(8)));
typedef _Float16 f16x8 __attribute__((ext_vector_type(8)));
typedef float f32x4 __attribute__((ext_vector_type(4)));

__device__ __forceinline__ float sigm(float x) { return 1.f / (1.f + __expf(-x)); }
__device__ __forceinline__ float ftanh(float x) {
    float t = __expf(-2.f * fabsf(x));
    float r = (1.f - t) / (1.f + t);
    return copysignf(r, x);
}
__device__ __forceinline__ u16 f2h(float v) {            // f32 -> f16 RTNE
    _Float16 h = (_Float16)v;
    return *(u16*)&h;
}
// write-through stores (agent-visible at vmcnt drain), exact cache bits
__device__ __forceinline__ void st16(u16* p, u32 v) {
    asm volatile("global_store_short %0, %1, off sc0 sc1" :: "v"(p), "v"(v) : "memory");
}
__device__ __forceinline__ void st128(u16* p, u16x8 v) {
    asm volatile("global_store_dwordx4 %0, %1, off sc0 sc1" :: "v"(p), "v"(v) : "memory");
}

// Fragment-major fp16 H layout, 16-row frags (1 KB each).
// frag f = ((g*4 + w)*NCH + ch); element (row16 r, kk 0..31):
//   lane' = r | ((kk>>3)<<4), j = kk&7; u16 idx = f*512 + lane'*8 + j.
__device__ __forceinline__ u32 hword16(int row, int k) {
    int g = row >> 6, w = (row >> 4) & 3, r = row & 15;
    int ch = k >> 5, kk = k & 31;
    return (u32)(((g * 4 + w) * NCH + ch) * 512)
         + (u32)(((r | ((kk >> 3) << 4)) << 3) + (kk & 7));
}

// ---------- prep: W -> transposed, K-reordered, fp16 ----------
__global__ __launch_bounds__(256) void prep_w(const float* __restrict__ W,
                                              u16* __restrict__ Wt) {
    int o = blockIdx.x * 256 + threadIdx.x;            // over ZC*KP
    if (o >= ZC * KP) return;
    int n = o / KP, k = o % KP;
    float v = 0.f;
    if (k < NCELL)              v = W[(size_t)(NFEAT + k) * ZC + n];   // h rows
    else if (k < NCELL + NFEAT) v = W[(size_t)(k - NCELL) * ZC + n];   // x rows
    Wt[o] = f2h(v);
}

// ---------- prep: H0 = [h=0 | x_0 | pad=0], H1 = 0 (fragment-major fp16) ----------
__global__ __launch_bounds__(256) void prep_h(const float* __restrict__ X,
                                              u16* __restrict__ H0, u16* __restrict__ H1) {
    int o = blockIdx.x * 256 + threadIdx.x;            // over BATCH*KP
    if (o >= BATCH * KP) return;
    int row = o / KP, k = o % KP;
    u16 b = 0;
    if (k >= NCELL && k < NCELL + NFEAT)
        b = f2h(X[(size_t)row * (SEQ * NFEAT) + (k - NCELL)]);   // t = 0
    u32 w = hword16(row, k);
    H0[w] = b;
    H1[w] = 0;
}

// ---------- persistent LSTM: fp16, 16 groups x 64 rows, 128 z-cols/WG,
// B chunks 0..RCH-1 resident in VGPRs (halves LDS-pipe traffic) ----------
__global__ __launch_bounds__(256, 1) void lstm_persist(
    u16* __restrict__ H0, u16* __restrict__ H1,
    const u16* __restrict__ Wt,                                  // [ZC][KP] fp16
    const float* __restrict__ bias,                              // [ZC]
    const float* __restrict__ X,                                 // [BATCH][SEQ][NFEAT]
    float* __restrict__ hf32,                                    // [BATCH][NCELL]
    int* __restrict__ bar)                                       // 16 x 64 ints
{
    extern __shared__ u16 Ws[];   // [128 cols][KL] fp16 swizzled | Hs: 4 x 512 u16

    const int tid = (int)threadIdx.x;
    const int bid = (int)blockIdx.x;
    const int g = bid & 15, nb2 = bid >> 4;   // group, col-block slot
    const int r0 = g * 64;
    const int lane = tid & 63, wv = tid >> 6;
    u16* __restrict__ Hs = Ws + 128 * KL;     // per-wave 512-u16 staging tiles
    int* __restrict__ bcnt   = bar + g * 64;
    int* __restrict__ bepoch = bar + g * 64 + 32;

    // ---- load W slice into LDS once (swizzled) ----
    for (int e = tid; e < 128 * (KP / 8); e += 256) {
        int col = e / (KP / 8), k8 = (e % (KP / 8)) * 8;
        int n = col >> 4, cl = col & 15;
        int zc = (n & 3) * NCELL + nb2 * 32 + (n >> 2) * 16 + cl;
        int so = k8 ^ ((col & 7) << 3);
        *(u16x8*)&Ws[col * KL + so] = *(const u16x8*)&Wt[(size_t)zc * KP + k8];
    }
    __syncthreads();

    const int cell0 = nb2 * 32 + (lane & 15);
    const int cell1 = cell0 + 16;
    const float bi0 = bias[cell0],           bi1 = bias[cell1];
    const float bj0 = bias[NCELL + cell0],   bj1 = bias[NCELL + cell1];
    const float bf0 = bias[2*NCELL + cell0], bf1 = bias[2*NCELL + cell1];
    const float bo0 = bias[3*NCELL + cell0], bo1 = bias[3*NCELL + cell1];

    const int akof = (lane >> 4) * 8;                 // k sub-offset for B frags (u16)
    // A-load base (u64 units): frag*128 + lane*2
    const u32 abase = (u32)((g * 4 + wv) * NCH) * 128u + (u32)lane * 2u;

    // epilogue: this wave fills exactly frag ((g*4+wv)*NCH + nb2)
    const u32 esto = (u32)((g * 4 + wv) * NCH + nb2) * 512u + (u32)lane * 8u;
    const int hsw = (wv << 9);                        // this wave's Hs tile

#define WSOFF(cb, off) ((cb) * KL + (((off)) ^ (((cb) & 7) << 3)))

    // ---- persistent B fragments for chunks 0..RCH-1 (loop-invariant W) ----
    f16x8 Breg[RCH][8];
    #pragma unroll
    for (int ch = 0; ch < RCH; ++ch)
        #pragma unroll
        for (int n = 0; n < 8; ++n)
            Breg[ch][n] = *(const f16x8*)&Ws[WSOFF(n * 16 + (lane & 15), ch * 32 + akof)];

    float ct[2][4] = {};   // persistent cell state [ch16][r]

    for (int t = 0; t < SEQ; ++t) {
        const u64* Hq = (const u64*)((t & 1) ? H1 : H0);
        u16*       Np = (t & 1) ? H0 : H1;

        f32x4 acc[8] = {};                         // [n] = [ch16*4 + gate]
        __attribute__((aligned(16))) u64 fr[NBUF][2];  // A ring

#define ALOADS(f, ch) do { \
        f[0] = __hip_atomic_load(&Hq[abase + (u32)(ch) * 128u],     __ATOMIC_RELAXED, __HIP_MEMORY_SCOPE_AGENT); \
        f[1] = __hip_atomic_load(&Hq[abase + (u32)(ch) * 128u + 1], __ATOMIC_RELAXED, __HIP_MEMORY_SCOPE_AGENT); \
        } while (0)
#define CCOMP(f, ch) do { \
        f16x8 a = *(const f16x8*)&f[0]; \
        _Pragma("unroll") \
        for (int n = 0; n < 8; ++n) { \
            f16x8 bn; \
            if ((ch) < RCH) bn = Breg[(ch) % RCH][n]; \
            else bn = *(const f16x8*)&Ws[WSOFF(n * 16 + (lane & 15), (ch) * 32 + akof)]; \
            acc[n] = __builtin_amdgcn_mfma_f32_16x16x32_f16(a, bn, acc[n], 0, 0, 0); \
        } } while (0)

        ALOADS(fr[0], 0); ALOADS(fr[1], 1); ALOADS(fr[2], 2);
        ALOADS(fr[3], 3); ALOADS(fr[4], 4); ALOADS(fr[5], 5);
        #pragma unroll
        for (int ch = 0; ch < NCH; ++ch) {
            if (ch + PFD < NCH) ALOADS(fr[(ch + PFD) % NBUF], ch + PFD);
            CCOMP(fr[ch % NBUF], ch);
        }
#undef ALOADS
#undef CCOMP

        // Fused gate epilogue; c in registers. TF gate order: i, j, f, o.
        #pragma unroll
        for (int c2 = 0; c2 < 2; ++c2) {
            #pragma unroll
            for (int r = 0; r < 4; ++r) {
                int row16 = (lane >> 4) * 4 + r;
                float zi = acc[c2 * 4 + 0][r] + (c2 ? bi1 : bi0);
                float zj = acc[c2 * 4 + 1][r] + (c2 ? bj1 : bj0);
                float zf = acc[c2 * 4 + 2][r] + (c2 ? bf1 : bf0);
                float zo = acc[c2 * 4 + 3][r] + (c2 ? bo1 : bo0);
                float cn = ct[c2][r] * sigm(zf + 1.0f) + sigm(zi) * ftanh(zj);
                ct[c2][r] = cn;
                float h = ftanh(cn) * sigm(zo);
                // Hs image of the frag: lane' = row16 | ((c2*2 + (cl>>3))<<4), j = cl&7
                Hs[hsw + ((row16 | ((c2 * 2 + ((lane >> 3) & 1)) << 4)) << 3) + (lane & 7)] = f2h(h);
                if (t == SEQ - 1) {
                    int row = r0 + wv * 16 + row16;
                    hf32[(size_t)row * NCELL + (c2 ? cell1 : cell0)] = h;
                }
            }
        }
        // readback and store the wave's full 1 KB frag in one b128/lane
        {
            u16x8 v = *(const u16x8*)&Hs[hsw + lane * 8];
            st128(&Np[esto], v);
        }
        // Stage next step's x-slice (chunk 16), spread over all 16 WGs.
        if (t + 1 < SEQ && tid < 96) {
            int e = nb2 * 96 + tid;                  // 0..1535 over 64 rows x 24 feats
            int rowg = e / 24, kk = e % 24;
            int row = r0 + rowg;
            float v = X[(size_t)row * (SEQ * NFEAT) + (t + 1) * NFEAT + kk];
            int w2 = rowg >> 4, r16 = rowg & 15;
            u32 idx = (u32)((g * 4 + w2) * NCH + 16) * 512u
                    + (u32)(((r16 | ((kk >> 3) << 4)) << 3) + (kk & 7));
            st16(&Np[idx], (u32)f2h(v));
        }

        // ---- 16-WG group barrier: pure atomics, NO cache maintenance ----
        __syncthreads();   // vmcnt drained: write-through stores visible at L3
        if (tid == 0) {
            int n = __hip_atomic_fetch_add(bcnt, 1, __ATOMIC_RELAXED, __HIP_MEMORY_SCOPE_AGENT);
            if (n == GWG - 1) {
                __hip_atomic_store(bcnt, 0, __ATOMIC_RELAXED, __HIP_MEMORY_SCOPE_AGENT);
                __hip_atomic_store(bepoch, t + 1, __ATOMIC_RELAXED, __HIP_MEMORY_SCOPE_AGENT);
            } else {
                int spins = 0;
                while (__hip_atomic_load(bepoch, __ATOMIC_RELAXED, __HIP_MEMORY_SCOPE_AGENT) <= t) {
                    __builtin_amdgcn_s_sleep(2);
                    if (++spins > 20000000) break;   // bail out instead of hanging
                }
            }
        }
        __syncthreads();
        // no fence: next step's H reads are read-through atomics (always coherent)
    }
}

// ---------- fp32 tail GEMM: C = act(A @ Wm + bias), tile 64x64 ----------
template <int ACT>
__global__ __launch_bounds__(256) void gemm64(
    const float* __restrict__ A, const float* __restrict__ Wm,
    const float* __restrict__ bias, float* __restrict__ out,
    int M, int N, int K)
{
    __shared__ float Asf[32][65];
    __shared__ float Bsf[32][65];
    const int c0 = blockIdx.x * 64;
    const int r0 = blockIdx.y * 64;
    const int tid = (int)threadIdx.x;
    const int tx = tid & 15, ty = tid >> 4;

    float acc[4][4];
    #pragma unroll
    for (int r = 0; r < 4; ++r) { acc[r][0]=0.f; acc[r][1]=0.f; acc[r][2]=0.f; acc[r][3]=0.f; }

    for (int k0 = 0; k0 < K; k0 += 32) {
        #pragma unroll
        for (int i = 0; i < 8; ++i) {
            int e = tid + 256 * i;
            int row = e >> 5, kk = e & 31;
            Asf[kk][row] = A[(size_t)(r0 + row) * K + k0 + kk];
        }
        #pragma unroll
        for (int i = 0; i < 8; ++i) {
            int e = tid + 256 * i;
            int kk = e >> 6, cl = e & 63;
            Bsf[kk][cl] = Wm[(size_t)(k0 + kk) * N + c0 + cl];
        }
        __syncthreads();
        #pragma unroll
        for (int kk = 0; kk < 32; ++kk) {
            float b0 = Bsf[kk][tx*4], b1 = Bsf[kk][tx*4+1], b2 = Bsf[kk][tx*4+2], b3 = Bsf[kk][tx*4+3];
            #pragma unroll
            for (int r = 0; r < 4; ++r) {
                float a = Asf[kk][ty*4 + r];
                acc[r][0] = fmaf(a, b0, acc[r][0]);
                acc[r][1] = fmaf(a, b1, acc[r][1]);
                acc[r][2] = fmaf(a, b2, acc[r][2]);
                acc[r][3] = fmaf(a, b3, acc[r][3]);
            }
        }
        __syncthreads();
    }
    #pragma unroll
    for (int r = 0; r < 4; ++r) {
        int gr = r0 + ty * 4 + r;
        #pragma unroll
        for (int j = 0; j < 4; ++j) {
            int gc = c0 + tx * 4 + j;
            float v = acc[r][j] + bias[gc];
            if (ACT) v = fmaxf(v, 0.f);
            out[(size_t)gr * N + gc] = v;
        }
    }
}

extern "C" void kernel_launch(void* const* d_in, const int* in_sizes, int n_in,
                              void* d_out, int out_size, void* d_ws, size_t ws_size,
                              hipStream_t stream)
{
    const float* X  = (const float*)d_in[0];
    const float* Wl = (const float*)d_in[1];
    const float* bl = (const float*)d_in[2];
    const float* Wd = (const float*)d_in[3];
    const float* bd = (const float*)d_in[4];
    const float* Wp = (const float*)d_in[5];
    const float* bp = (const float*)d_in[6];
    float* out = (float*)d_out;

    // ws layout
    char* p = (char*)d_ws;
    int* bar      = (int*)p; p += 4096;                              // 16 groups x 256 B
    float* hf32   = (float*)p; p += (size_t)BATCH * NCELL * 4;       // 2 MB
    float* dense  = (float*)p; p += (size_t)BATCH * DENSE_N * 4;     // 8 MB
    u16* Wt   = (u16*)p; p += (size_t)ZC * KP * 2;                   // 2.23 MB fp16
    u16* H0   = (u16*)p; p += (size_t)BATCH * KP * 2;                // 1.11 MB
    u16* H1   = (u16*)p; p += (size_t)BATCH * KP * 2;

    (void)hipMemsetAsync(bar, 0, 4096, stream);
    prep_w<<<(ZC * KP) / 256, 256, 0, stream>>>(Wl, Wt);
    prep_h<<<(BATCH * KP) / 256, 256, 0, stream>>>(X, H0, H1);

    const int lds_bytes = 128 * KL * 2 + 4 * 512 * 2;   // 147456 + 4096 = 151552
    (void)hipFuncSetAttribute((const void*)lstm_persist,
                              hipFuncAttributeMaxDynamicSharedMemorySize, lds_bytes);
    lstm_persist<<<NWG, 256, lds_bytes, stream>>>(H0, H1, Wt, bl, X, hf32, bar);

    dim3 blk(256);
    gemm64<1><<<dim3(DENSE_N / 64, BATCH / 64), blk, 0, stream>>>(hf32, Wd, bd, dense, BATCH, DENSE_N, NCELL);
    gemm64<0><<<dim3(PRED_N / 64, BATCH / 64), blk, 0, stream>>>(dense, Wp, bp, out, BATCH, PRED_N, DENSE_N);
}

// Round 18
// 2696.209 us; speedup vs baseline: 1.2035x; 1.2035x over previous
//
#include <hip/hip_runtime.h>
#include <hip/hip_fp16.h>

#define BATCH 1024
#define SEQ 512
#define NFEAT 24
#define NCELL 512
#define ZC 2048      // 4*NCELL
#define KP 544       // reordered K: [h(512) | x(24) | pad(8)]
#define NCH 17       // K chunks of 32
#define KL 576       // LDS k-stride in u16 (XOR-swizzled in 16B units)
#define DENSE_N 2048
#define PRED_N 576
#define NWG 256
#define NGRP 16      // row groups (64 rows each)
#define GWG 16       // WGs per group (128 z-cols each)
#define PFD 6        // A-prefetch depth in chunks
#define NBUF 7       // PFD + 1

typedef unsigned short u16;
typedef unsigned int u32;
typedef unsigned long long u64;
typedef unsigned short u16x8 __attribute__((ext_vector_type(8)));
typedef _Float16 f16x8 __attribute__((ext_vector_type(8)));
typedef float f32x4 __attribute__((ext_vector_type(4)));

__device__ __forceinline__ float sigm(float x) { return 1.f / (1.f + __expf(-x)); }
__device__ __forceinline__ float ftanh(float x) {
    float t = __expf(-2.f * fabsf(x));
    float r = (1.f - t) / (1.f + t);
    return copysignf(r, x);
}
__device__ __forceinline__ u16 f2h(float v) {            // f32 -> f16 RTNE
    _Float16 h = (_Float16)v;
    return *(u16*)&h;
}
// write-through stores (agent-visible at vmcnt drain), exact cache bits
__device__ __forceinline__ void st16(u16* p, u32 v) {
    asm volatile("global_store_short %0, %1, off sc0 sc1" :: "v"(p), "v"(v) : "memory");
}
__device__ __forceinline__ void st64(u16* p, u64 v) {
    asm volatile("global_store_dwordx2 %0, %1, off sc0 sc1" :: "v"(p), "v"(v) : "memory");
}

// Fragment-major fp16 H layout, 16-row frags (1 KB each).
// frag f = ((g*4 + w)*NCH + ch); element (row16 r, kk 0..31):
//   lane' = r | ((kk>>3)<<4), j = kk&7; u16 idx = f*512 + lane'*8 + j.
__device__ __forceinline__ u32 hword16(int row, int k) {
    int g = row >> 6, w = (row >> 4) & 3, r = row & 15;
    int ch = k >> 5, kk = k & 31;
    return (u32)(((g * 4 + w) * NCH + ch) * 512)
         + (u32)(((r | ((kk >> 3) << 4)) << 3) + (kk & 7));
}

// ---------- prep: W -> transposed, K-reordered, fp16 ----------
__global__ __launch_bounds__(256) void prep_w(const float* __restrict__ W,
                                              u16* __restrict__ Wt) {
    int o = blockIdx.x * 256 + threadIdx.x;            // over ZC*KP
    if (o >= ZC * KP) return;
    int n = o / KP, k = o % KP;
    float v = 0.f;
    if (k < NCELL)              v = W[(size_t)(NFEAT + k) * ZC + n];   // h rows
    else if (k < NCELL + NFEAT) v = W[(size_t)(k - NCELL) * ZC + n];   // x rows
    Wt[o] = f2h(v);
}

// ---------- prep: H0 = [h=0 | x_0 | pad=0], H1 = 0 (fragment-major fp16) ----------
__global__ __launch_bounds__(256) void prep_h(const float* __restrict__ X,
                                              u16* __restrict__ H0, u16* __restrict__ H1) {
    int o = blockIdx.x * 256 + threadIdx.x;            // over BATCH*KP
    if (o >= BATCH * KP) return;
    int row = o / KP, k = o % KP;
    u16 b = 0;
    if (k >= NCELL && k < NCELL + NFEAT)
        b = f2h(X[(size_t)row * (SEQ * NFEAT) + (k - NCELL)]);   // t = 0
    u32 w = hword16(row, k);
    H0[w] = b;
    H1[w] = 0;
}

// ---------- persistent LSTM: fp16, 16 groups x 64 rows, 128 z-cols/WG,
// 512 threads (8 waves -> 2 waves/SIMD). Wave (fi,ci) = A-frag fi x cell-half ci.
__global__ __launch_bounds__(512, 1) void lstm_persist(
    u16* __restrict__ H0, u16* __restrict__ H1,
    const u16* __restrict__ Wt,                                  // [ZC][KP] fp16
    const float* __restrict__ bias,                              // [ZC]
    const float* __restrict__ X,                                 // [BATCH][SEQ][NFEAT]
    float* __restrict__ hf32,                                    // [BATCH][NCELL]
    int* __restrict__ bar)                                       // 16 x 64 ints
{
    extern __shared__ u16 Ws[];   // [128 cols][KL] fp16 swizzled | Hs: 8 x 256 u16

    const int tid = (int)threadIdx.x;
    const int bid = (int)blockIdx.x;
    const int g = bid & 15, nb2 = bid >> 4;   // group, col-block slot
    const int r0 = g * 64;
    const int lane = tid & 63, wv = tid >> 6;
    const int fi = wv >> 1, ci = wv & 1;      // A-frag index, cell-half
    u16* __restrict__ Hs = Ws + 128 * KL;     // per-wave 256-u16 staging tiles
    int* __restrict__ bcnt   = bar + g * 64;
    int* __restrict__ bepoch = bar + g * 64 + 32;

    // ---- load W slice into LDS once (swizzled) ----
    for (int e = tid; e < 128 * (KP / 8); e += 512) {
        int col = e / (KP / 8), k8 = (e % (KP / 8)) * 8;
        int n = col >> 4, cl = col & 15;
        int zc = (n & 3) * NCELL + nb2 * 32 + (n >> 2) * 16 + cl;
        int so = k8 ^ ((col & 7) << 3);
        *(u16x8*)&Ws[col * KL + so] = *(const u16x8*)&Wt[(size_t)zc * KP + k8];
    }
    __syncthreads();

    const int cell = nb2 * 32 + ci * 16 + (lane & 15);
    const float bi = bias[cell], bj = bias[NCELL + cell];
    const float bf_ = bias[2 * NCELL + cell], bo = bias[3 * NCELL + cell];

    const int akof = (lane >> 4) * 8;                 // k sub-offset for B frags (u16)
    // A-load base (u64 units): frag*128 + lane*2
    const u32 abase = (u32)((g * 4 + fi) * NCH) * 128u + (u32)lane * 2u;

    // epilogue: wave writes half-frag ci of frag ((g*4+fi)*NCH + nb2)
    const u32 esto = (u32)((g * 4 + fi) * NCH + nb2) * 512u + (u32)ci * 256u + (u32)lane * 4u;
    const int hsw = (wv << 8);                        // this wave's Hs tile (256 u16)

#define WSOFF(cb, off) ((cb) * KL + (((off)) ^ (((cb) & 7) << 3)))

    float ct[4] = {};   // persistent cell state [r]

    for (int t = 0; t < SEQ; ++t) {
        const u64* Hq = (const u64*)((t & 1) ? H1 : H0);
        u16*       Np = (t & 1) ? H0 : H1;

        f32x4 acc[4] = {};                         // [gate]
        __attribute__((aligned(16))) u64 fr[NBUF][2];  // A ring

#define ALOADS(f, ch) do { \
        f[0] = __hip_atomic_load(&Hq[abase + (u32)(ch) * 128u],     __ATOMIC_RELAXED, __HIP_MEMORY_SCOPE_AGENT); \
        f[1] = __hip_atomic_load(&Hq[abase + (u32)(ch) * 128u + 1], __ATOMIC_RELAXED, __HIP_MEMORY_SCOPE_AGENT); \
        } while (0)
#define CCOMP(f, ch) do { \
        f16x8 a = *(const f16x8*)&f[0]; \
        _Pragma("unroll") \
        for (int gt = 0; gt < 4; ++gt) { \
            f16x8 bn = *(const f16x8*)&Ws[WSOFF((ci * 4 + gt) * 16 + (lane & 15), (ch) * 32 + akof)]; \
            acc[gt] = __builtin_amdgcn_mfma_f32_16x16x32_f16(a, bn, acc[gt], 0, 0, 0); \
        } } while (0)

        ALOADS(fr[0], 0); ALOADS(fr[1], 1); ALOADS(fr[2], 2);
        ALOADS(fr[3], 3); ALOADS(fr[4], 4); ALOADS(fr[5], 5);
        #pragma unroll
        for (int ch = 0; ch < NCH; ++ch) {
            if (ch + PFD < NCH) ALOADS(fr[(ch + PFD) % NBUF], ch + PFD);
            CCOMP(fr[ch % NBUF], ch);
        }
#undef ALOADS
#undef CCOMP

        // Fused gate epilogue; c in registers. TF gate order: i, j, f, o.
        #pragma unroll
        for (int r = 0; r < 4; ++r) {
            int row16 = (lane >> 4) * 4 + r;
            float zi = acc[0][r] + bi;
            float zj = acc[1][r] + bj;
            float zf = acc[2][r] + bf_;
            float zo = acc[3][r] + bo;
            float cn = ct[r] * sigm(zf + 1.0f) + sigm(zi) * ftanh(zj);
            ct[r] = cn;
            float h = ftanh(cn) * sigm(zo);
            // half-frag local image: lane'' = row16 | ((cl>>3)<<4), j = cl&7
            Hs[hsw + ((row16 | (((lane >> 3) & 1) << 4)) << 3) + (lane & 7)] = f2h(h);
            if (t == SEQ - 1) {
                int row = r0 + fi * 16 + row16;
                hf32[(size_t)row * NCELL + cell] = h;
            }
        }
        // readback and store the wave's contiguous 512 B half-frag (8 B/lane)
        {
            u64 v = *(const u64*)&Hs[hsw + lane * 4];
            st64(&Np[esto], v);
        }
        // Stage next step's x-slice (chunk 16), spread over all 16 WGs.
        if (t + 1 < SEQ && tid < 96) {
            int e = nb2 * 96 + tid;                  // 0..1535 over 64 rows x 24 feats
            int rowg = e / 24, kk = e % 24;
            int row = r0 + rowg;
            float v = X[(size_t)row * (SEQ * NFEAT) + (t + 1) * NFEAT + kk];
            int w2 = rowg >> 4, r16 = rowg & 15;
            u32 idx = (u32)((g * 4 + w2) * NCH + 16) * 512u
                    + (u32)(((r16 | ((kk >> 3) << 4)) << 3) + (kk & 7));
            st16(&Np[idx], (u32)f2h(v));
        }

        // ---- 16-WG group barrier: pure atomics, NO cache maintenance ----
        __syncthreads();   // vmcnt drained: write-through stores visible at L3
        if (tid == 0) {
            int n = __hip_atomic_fetch_add(bcnt, 1, __ATOMIC_RELAXED, __HIP_MEMORY_SCOPE_AGENT);
            if (n == GWG - 1) {
                __hip_atomic_store(bcnt, 0, __ATOMIC_RELAXED, __HIP_MEMORY_SCOPE_AGENT);
                __hip_atomic_store(bepoch, t + 1, __ATOMIC_RELAXED, __HIP_MEMORY_SCOPE_AGENT);
            } else {
                int spins = 0;
                while (__hip_atomic_load(bepoch, __ATOMIC_RELAXED, __HIP_MEMORY_SCOPE_AGENT) <= t) {
                    __builtin_amdgcn_s_sleep(2);
                    if (++spins > 20000000) break;   // bail out instead of hanging
                }
            }
        }
        __syncthreads();
        // no fence: next step's H reads are read-through atomics (always coherent)
    }
}

// ---------- fp32 tail GEMM: C = act(A @ Wm + bias), tile 64x64 ----------
template <int ACT>
__global__ __launch_bounds__(256) void gemm64(
    const float* __restrict__ A, const float* __restrict__ Wm,
    const float* __restrict__ bias, float* __restrict__ out,
    int M, int N, int K)
{
    __shared__ float Asf[32][65];
    __shared__ float Bsf[32][65];
    const int c0 = blockIdx.x * 64;
    const int r0 = blockIdx.y * 64;
    const int tid = (int)threadIdx.x;
    const int tx = tid & 15, ty = tid >> 4;

    float acc[4][4];
    #pragma unroll
    for (int r = 0; r < 4; ++r) { acc[r][0]=0.f; acc[r][1]=0.f; acc[r][2]=0.f; acc[r][3]=0.f; }

    for (int k0 = 0; k0 < K; k0 += 32) {
        #pragma unroll
        for (int i = 0; i < 8; ++i) {
            int e = tid + 256 * i;
            int row = e >> 5, kk = e & 31;
            Asf[kk][row] = A[(size_t)(r0 + row) * K + k0 + kk];
        }
        #pragma unroll
        for (int i = 0; i < 8; ++i) {
            int e = tid + 256 * i;
            int kk = e >> 6, cl = e & 63;
            Bsf[kk][cl] = Wm[(size_t)(k0 + kk) * N + c0 + cl];
        }
        __syncthreads();
        #pragma unroll
        for (int kk = 0; kk < 32; ++kk) {
            float b0 = Bsf[kk][tx*4], b1 = Bsf[kk][tx*4+1], b2 = Bsf[kk][tx*4+2], b3 = Bsf[kk][tx*4+3];
            #pragma unroll
            for (int r = 0; r < 4; ++r) {
                float a = Asf[kk][ty*4 + r];
                acc[r][0] = fmaf(a, b0, acc[r][0]);
                acc[r][1] = fmaf(a, b1, acc[r][1]);
                acc[r][2] = fmaf(a, b2, acc[r][2]);
                acc[r][3] = fmaf(a, b3, acc[r][3]);
            }
        }
        __syncthreads();
    }
    #pragma unroll
    for (int r = 0; r < 4; ++r) {
        int gr = r0 + ty * 4 + r;
        #pragma unroll
        for (int j = 0; j < 4; ++j) {
            int gc = c0 + tx * 4 + j;
            float v = acc[r][j] + bias[gc];
            if (ACT) v = fmaxf(v, 0.f);
            out[(size_t)gr * N + gc] = v;
        }
    }
}

extern "C" void kernel_launch(void* const* d_in, const int* in_sizes, int n_in,
                              void* d_out, int out_size, void* d_ws, size_t ws_size,
                              hipStream_t stream)
{
    const float* X  = (const float*)d_in[0];
    const float* Wl = (const float*)d_in[1];
    const float* bl = (const float*)d_in[2];
    const float* Wd = (const float*)d_in[3];
    const float* bd = (const float*)d_in[4];
    const float* Wp = (const float*)d_in[5];
    const float* bp = (const float*)d_in[6];
    float* out = (float*)d_out;

    // ws layout
    char* p = (char*)d_ws;
    int* bar      = (int*)p; p += 4096;                              // 16 groups x 256 B
    float* hf32   = (float*)p; p += (size_t)BATCH * NCELL * 4;       // 2 MB
    float* dense  = (float*)p; p += (size_t)BATCH * DENSE_N * 4;     // 8 MB
    u16* Wt   = (u16*)p; p += (size_t)ZC * KP * 2;                   // 2.23 MB fp16
    u16* H0   = (u16*)p; p += (size_t)BATCH * KP * 2;                // 1.11 MB
    u16* H1   = (u16*)p; p += (size_t)BATCH * KP * 2;

    (void)hipMemsetAsync(bar, 0, 4096, stream);
    prep_w<<<(ZC * KP) / 256, 256, 0, stream>>>(Wl, Wt);
    prep_h<<<(BATCH * KP) / 256, 256, 0, stream>>>(X, H0, H1);

    const int lds_bytes = 128 * KL * 2 + 8 * 256 * 2;   // 147456 + 4096 = 151552
    (void)hipFuncSetAttribute((const void*)lstm_persist,
                              hipFuncAttributeMaxDynamicSharedMemorySize, lds_bytes);
    lstm_persist<<<NWG, 512, lds_bytes, stream>>>(H0, H1, Wt, bl, X, hf32, bar);

    dim3 blk(256);
    gemm64<1><<<dim3(DENSE_N / 64, BATCH / 64), blk, 0, stream>>>(hf32, Wd, bd, dense, BATCH, DENSE_N, NCELL);
    gemm64<0><<<dim3(PRED_N / 64, BATCH / 64), blk, 0, stream>>>(dense, Wp, bp, out, BATCH, PRED_N, DENSE_N);
}